// Round 6
// baseline (118.808 us; speedup 1.0000x reference)
//
#include <hip/hip_runtime.h>
#include <hip/hip_bf16.h>
#include <stdint.h>

typedef __bf16 bf16;
typedef __bf16 bf16x8 __attribute__((ext_vector_type(8)));
typedef __bf16 bf16x4 __attribute__((ext_vector_type(4)));
typedef __bf16 bf16x2 __attribute__((ext_vector_type(2)));
typedef float  f32x4  __attribute__((ext_vector_type(4)));
typedef float  f32x16 __attribute__((ext_vector_type(16)));
typedef unsigned int uint;

#define MFMA(a,b,c)   __builtin_amdgcn_mfma_f32_16x16x32_bf16((a),(b),(c),0,0,0)
#define MFMA32(a,b,c) __builtin_amdgcn_mfma_f32_32x32x16_bf16((a),(b),(c),0,0,0)
#define EXP2(x)       __builtin_amdgcn_exp2f(x)

__device__ __forceinline__ void gload_lds16(const void* g, void* lds) {
  __builtin_amdgcn_global_load_lds(
      (const __attribute__((address_space(1))) uint32_t*)g,
      (__attribute__((address_space(3))) uint32_t*)lds, 16, 0, 0);
}

__device__ __forceinline__ uint pk_bf16(float lo, float hi) {
  bf16x2 v; v[0] = (bf16)lo; v[1] = (bf16)hi;
  return __builtin_bit_cast(uint, v);
}

// ---------------- convert fp32 -> bf16 (x + 4 weights) ----------------
__global__ __launch_bounds__(256) void k_cvt(
    const float* __restrict__ x,
    const float* __restrict__ wq, const float* __restrict__ wk,
    const float* __restrict__ wv, const float* __restrict__ wo,
    bf16* __restrict__ xb, bf16* __restrict__ wqb, bf16* __restrict__ wkb,
    bf16* __restrict__ wvb, bf16* __restrict__ wob)
{
  int r = blockIdx.y;
  const float* s; bf16* d; int n;
  switch (r) {
    case 0: s = x;  d = xb;  n = 4194304; break;
    case 1: s = wq; d = wqb; n = 1048576; break;
    case 2: s = wk; d = wkb; n = 1048576; break;
    case 3: s = wv; d = wvb; n = 1048576; break;
    default: s = wo; d = wob; n = 1048576; break;
  }
  int i = (blockIdx.x * 256 + threadIdx.x) * 8;
  if (i >= n) return;
  const float4* sp = (const float4*)(s + i);
  float4 a = sp[0], b = sp[1];
  bf16x8 o;
  o[0]=(bf16)a.x; o[1]=(bf16)a.y; o[2]=(bf16)a.z; o[3]=(bf16)a.w;
  o[4]=(bf16)b.x; o[5]=(bf16)b.y; o[6]=(bf16)b.z; o[7]=(bf16)b.w;
  *(bf16x8*)(d + i) = o;
}

// ---------------- fused QKV projection GEMM (2-phase pipelined, BK=64) ------
// 128x128 tile, 4 waves, double-buffered swizzled LDS, 1 barrier/K-step.
// Q written scaled by log2(e)/32 into [b,h,n,d]; K into [b,h,n,d]; V into [b,h,d,n].
__global__ __launch_bounds__(256, 1) void k_gemm_qkv(
    const bf16* __restrict__ A,
    const bf16* __restrict__ Wq, const bf16* __restrict__ Wk, const bf16* __restrict__ Wv,
    const float* __restrict__ bq, const float* __restrict__ bk, const float* __restrict__ bv,
    bf16* __restrict__ Qw, bf16* __restrict__ Kw, bf16* __restrict__ Vtw)
{
  __shared__ __align__(16) char As[2][16384];
  __shared__ __align__(16) char Bs[2][16384];
  int tid = threadIdx.x;
  int wv4 = tid >> 6, l = tid & 63, lo = l & 15, hi = l >> 4;
  int mt = blockIdx.x;           // 0..31
  int ft = blockIdx.y;           // 0..23
  int wsel = ft >> 3;
  const bf16* W = (wsel == 0) ? Wq : (wsel == 1) ? Wk : Wv;
  const float* bias = (wsel == 0) ? bq : (wsel == 1) ? bk : bv;
  int f0 = (ft & 7) * 128;
  const bf16* Ab = A + (size_t)mt * 128 * 1024;
  const bf16* Wb = W + (size_t)f0 * 1024;
  int wm = wv4 >> 1, wf = wv4 & 1;
  f32x4 acc[4][4];
  #pragma unroll
  for (int i = 0; i < 4; i++)
    #pragma unroll
    for (int j = 0; j < 4; j++) acc[i][j] = (f32x4){0.f, 0.f, 0.f, 0.f};

  // staging: 1024 16B-slots per matrix; slot sp=(row<<3|s) <- global col 8*(s^(row&7))
  #define STAGEG(t, bi) {                                              \
    int k0 = (t) * 64;                                                 \
    _Pragma("unroll")                                                  \
    for (int p = 0; p < 4; p++) {                                      \
      int sp = p * 256 + tid;                                          \
      int row = sp >> 3, s = sp & 7;                                   \
      int gc = k0 + 8 * (s ^ (row & 7));                               \
      gload_lds16(Ab + (size_t)row * 1024 + gc, As[bi] + sp * 16);     \
      gload_lds16(Wb + (size_t)row * 1024 + gc, Bs[bi] + sp * 16);     \
    } }

  STAGEG(0, 0);
  for (int t = 0; t < 16; ++t) {
    __syncthreads();                    // drains STAGE(t): buf t&1 ready
    if (t < 15) STAGEG(t + 1, (t + 1) & 1);   // fly during compute
    const char* Ac = As[t & 1];
    const char* Bc = Bs[t & 1];
    #pragma unroll
    for (int kk = 0; kk < 2; kk++) {
      bf16x8 af[4], bfr[4];
      #pragma unroll
      for (int ms = 0; ms < 4; ms++) {
        int row = wm * 64 + ms * 16 + lo;
        af[ms] = *(const bf16x8*)(Ac + row * 128 + 16 * ((kk * 4 + hi) ^ (row & 7)));
      }
      #pragma unroll
      for (int fs = 0; fs < 4; fs++) {
        int row = wf * 64 + fs * 16 + lo;
        bfr[fs] = *(const bf16x8*)(Bc + row * 128 + 16 * ((kk * 4 + hi) ^ (row & 7)));
      }
      __builtin_amdgcn_s_setprio(1);
      #pragma unroll
      for (int ms = 0; ms < 4; ms++)
        #pragma unroll
        for (int fs = 0; fs < 4; fs++)
          acc[ms][fs] = MFMA(af[ms], bfr[fs], acc[ms][fs]);
      __builtin_amdgcn_s_setprio(0);
    }
  }
  #undef STAGEG

  float bv4[4];
  #pragma unroll
  for (int fs = 0; fs < 4; fs++) bv4[fs] = bias[f0 + wf * 64 + fs * 16 + lo];
  #pragma unroll
  for (int ms = 0; ms < 4; ms++) {
    #pragma unroll
    for (int fs = 0; fs < 4; fs++) {
      int fl = f0 + wf * 64 + fs * 16 + lo;
      int h = fl >> 6, dd = fl & 63;
      #pragma unroll
      for (int r = 0; r < 4; r++) {
        int m = mt * 128 + wm * 64 + ms * 16 + hi * 4 + r;
        int b = m >> 11, n = m & 2047;
        float val = acc[ms][fs][r] + bv4[fs];
        if (wsel == 0)      Qw[(((size_t)(b * 16 + h) * 2048 + n) * 64) + dd] = (bf16)(val * 0.0450842199527801f);
        else if (wsel == 1) Kw[(((size_t)(b * 16 + h) * 2048 + n) * 64) + dd] = (bf16)val;
        else                Vtw[(((size_t)(b * 16 + h) * 64 + dd) * 2048) + n] = (bf16)val;
      }
    }
  }
}

// ---------------- flash attention v4: 32q/wave, 2 blocks/CU, dbuf, max-free --
__global__ __launch_bounds__(256, 2) void k_attn(
    const bf16* __restrict__ Q, const bf16* __restrict__ K,
    const bf16* __restrict__ Vt, bf16* __restrict__ O)
{
  __shared__ __align__(16) char Ks[2][8192];
  __shared__ __align__(16) char Vs[2][8192];
  int tid = threadIdx.x;
  int wid = tid >> 6, l = tid & 63;
  int lq = l & 31, hi1 = l >> 5;
  int qt = blockIdx.x, bh = blockIdx.y;
  int qg = qt * 128 + wid * 32 + lq;
  const bf16* Kb = K + (size_t)bh * 2048 * 64;
  const bf16* Vb = Vt + (size_t)bh * 64 * 2048;

  bf16x8 qf[4];
  const bf16* Qb = Q + ((size_t)bh * 2048 + qg) * 64 + hi1 * 8;
  #pragma unroll
  for (int c = 0; c < 4; c++) qf[c] = *(const bf16x8*)(Qb + 16 * c);

  f32x16 o0, o1, zz;
  #pragma unroll
  for (int r = 0; r < 16; r++) { zz[r] = 0.f; o0[r] = 0.f; o1[r] = 0.f; }
  float ls = 0.f;

  int srow = tid >> 3, slot = tid & 7;
  int swz = 16 * (slot ^ (srow & 7));
  int swk = lq & 7;
  uint4 k0r, k1r, v0r, v1r;
  #define STAGE(t) {                                                          \
    k0r = *(const uint4*)(Kb + (size_t)((t)*64 + srow) * 64 + slot * 8);      \
    k1r = *(const uint4*)(Kb + (size_t)((t)*64 + srow + 32) * 64 + slot * 8); \
    v0r = *(const uint4*)(Vb + (size_t)srow * 2048 + (t)*64 + slot * 8);      \
    v1r = *(const uint4*)(Vb + (size_t)(srow + 32) * 2048 + (t)*64 + slot * 8); }
  #define WRBUF(bi) {                                  \
    *(uint4*)(Ks[bi] + srow * 128 + swz)        = k0r; \
    *(uint4*)(Ks[bi] + (srow + 32) * 128 + swz) = k1r; \
    *(uint4*)(Vs[bi] + srow * 128 + swz)        = v0r; \
    *(uint4*)(Vs[bi] + (srow + 32) * 128 + swz) = v1r; }
  #define EXPSUM(S, T0, T1, T2, T3)                     \
    _Pragma("unroll")                                   \
    for (int r = 0; r < 16; r += 4) {                   \
      S[r]   = EXP2(S[r]);   T0 += S[r];                \
      S[r+1] = EXP2(S[r+1]); T1 += S[r+1];              \
      S[r+2] = EXP2(S[r+2]); T2 += S[r+2];              \
      S[r+3] = EXP2(S[r+3]); T3 += S[r+3];              \
    }
  #define PACK(dst, plo, phi)                                                \
    _Pragma("unroll")                                                        \
    for (int m = 0; m < 2; m++) {                                            \
      uint a0 = pk_bf16(plo[8*m+0], plo[8*m+1]);                             \
      uint b0 = pk_bf16(plo[8*m+4], plo[8*m+5]);                             \
      asm volatile("v_permlane32_swap_b32 %0, %1" : "+v"(a0), "+v"(b0));     \
      uint a1 = pk_bf16(plo[8*m+2], plo[8*m+3]);                             \
      uint b1 = pk_bf16(plo[8*m+6], plo[8*m+7]);                             \
      asm volatile("v_permlane32_swap_b32 %0, %1" : "+v"(a1), "+v"(b1));     \
      dst[m] = (uint4){a0, a1, b0, b1};                                      \
      uint c0 = pk_bf16(phi[8*m+0], phi[8*m+1]);                             \
      uint d0 = pk_bf16(phi[8*m+4], phi[8*m+5]);                             \
      asm volatile("v_permlane32_swap_b32 %0, %1" : "+v"(c0), "+v"(d0));     \
      uint c1 = pk_bf16(phi[8*m+2], phi[8*m+3]);                             \
      uint d1 = pk_bf16(phi[8*m+6], phi[8*m+7]);                             \
      asm volatile("v_permlane32_swap_b32 %0, %1" : "+v"(c1), "+v"(d1));     \
      dst[2+m] = (uint4){c0, c1, d0, d1};                                    \
    }

  STAGE(0);
  WRBUF(0);
  STAGE(1);

  for (int t = 0; t < 32; ++t) {
    __syncthreads();
    const char* Kc = Ks[t & 1];
    const char* Vc = Vs[t & 1];

    bf16x8 kf0[4], kf1[4];
    #pragma unroll
    for (int c = 0; c < 4; c++) {
      kf0[c] = *(const bf16x8*)(Kc + lq * 128 + 16 * ((2*c + hi1) ^ swk));
      kf1[c] = *(const bf16x8*)(Kc + (32 + lq) * 128 + 16 * ((2*c + hi1) ^ swk));
    }

    __builtin_amdgcn_s_setprio(1);
    f32x16 s0 = MFMA32(kf0[0], qf[0], zz);
    f32x16 s1 = MFMA32(kf1[0], qf[0], zz);
    #pragma unroll
    for (int c = 1; c < 4; c++) {
      s0 = MFMA32(kf0[c], qf[c], s0);
      s1 = MFMA32(kf1[c], qf[c], s1);
    }
    __builtin_amdgcn_s_setprio(0);

    float t0 = 0.f, t1 = 0.f, t2 = 0.f, t3 = 0.f;
    EXPSUM(s0, t0, t1, t2, t3);
    EXPSUM(s1, t0, t1, t2, t3);
    ls += (t0 + t1) + (t2 + t3);

    uint4 pf[4];
    PACK(pf, s0, s1);

    __builtin_amdgcn_s_setprio(1);
    #pragma unroll
    for (int c = 0; c < 4; c++) {
      bf16x8 pb = __builtin_bit_cast(bf16x8, pf[c]);
      bf16x8 vf0 = *(const bf16x8*)(Vc + lq * 128 + 16 * ((2*c + hi1) ^ swk));
      o0 = MFMA32(vf0, pb, o0);
      bf16x8 vf1 = *(const bf16x8*)(Vc + (32 + lq) * 128 + 16 * ((2*c + hi1) ^ swk));
      o1 = MFMA32(vf1, pb, o1);
    }
    __builtin_amdgcn_s_setprio(0);

    if (t < 31) {
      WRBUF((t + 1) & 1);
      if (t < 30) STAGE(t + 2);
    }
  }
  #undef STAGE
  #undef WRBUF

  float lsum = ls + __shfl_xor(ls, 32);
  float inv = 1.0f / lsum;
  int b = bh >> 4, h = bh & 15;
  bf16* Ob = O + ((size_t)(b * 2048 + qg)) * 1024 + h * 64 + hi1 * 4;
  #pragma unroll
  for (int g = 0; g < 4; g++) {
    bf16x4 w0, w1;
    #pragma unroll
    for (int j = 0; j < 4; j++) {
      w0[j] = (bf16)(o0[4*g+j] * inv);
      w1[j] = (bf16)(o1[4*g+j] * inv);
    }
    *(bf16x4*)(Ob + g * 8)      = w0;
    *(bf16x4*)(Ob + 32 + g * 8) = w1;
  }
}

// ---------------- output projection GEMM (2-phase pipelined, 512 thr) -------
// 128x128 tile, 8 waves (2Mx4F), BK=64; grid (32,8)=256 blocks -> 2 waves/SIMD.
__global__ __launch_bounds__(512, 1) void k_gemm_out(
    const bf16* __restrict__ A,      // O [4096][1024] bf16
    const bf16* __restrict__ W,      // Wo bf16 [1024][1024]
    const float* __restrict__ bias,  // bo
    float* __restrict__ Cout)        // [4096][1024] fp32
{
  __shared__ __align__(16) char As[2][16384];
  __shared__ __align__(16) char Bs[2][16384];
  int tid = threadIdx.x;
  int wid = tid >> 6, l = tid & 63, lo = l & 15, hi = l >> 4;
  int mt = blockIdx.x;           // 0..31
  int f0 = blockIdx.y * 128;     // 0..7 tiles
  const bf16* Ab = A + (size_t)mt * 128 * 1024;
  const bf16* Wb = W + (size_t)f0 * 1024;
  int wm = wid >> 2, wf = wid & 3;   // 2M x 4F; per-wave out 64x32
  f32x4 acc[4][2];
  #pragma unroll
  for (int i = 0; i < 4; i++)
    #pragma unroll
    for (int j = 0; j < 2; j++) acc[i][j] = (f32x4){0.f, 0.f, 0.f, 0.f};

  #define STAGEG(t, bi) {                                              \
    int k0 = (t) * 64;                                                 \
    _Pragma("unroll")                                                  \
    for (int p = 0; p < 2; p++) {                                      \
      int sp = p * 512 + tid;                                          \
      int row = sp >> 3, s = sp & 7;                                   \
      int gc = k0 + 8 * (s ^ (row & 7));                               \
      gload_lds16(Ab + (size_t)row * 1024 + gc, As[bi] + sp * 16);     \
      gload_lds16(Wb + (size_t)row * 1024 + gc, Bs[bi] + sp * 16);     \
    } }

  STAGEG(0, 0);
  for (int t = 0; t < 16; ++t) {
    __syncthreads();
    if (t < 15) STAGEG(t + 1, (t + 1) & 1);
    const char* Ac = As[t & 1];
    const char* Bc = Bs[t & 1];
    #pragma unroll
    for (int kk = 0; kk < 2; kk++) {
      bf16x8 af[4], bfr[2];
      #pragma unroll
      for (int ms = 0; ms < 4; ms++) {
        int row = wm * 64 + ms * 16 + lo;
        af[ms] = *(const bf16x8*)(Ac + row * 128 + 16 * ((kk * 4 + hi) ^ (row & 7)));
      }
      #pragma unroll
      for (int fs = 0; fs < 2; fs++) {
        int row = wf * 32 + fs * 16 + lo;
        bfr[fs] = *(const bf16x8*)(Bc + row * 128 + 16 * ((kk * 4 + hi) ^ (row & 7)));
      }
      __builtin_amdgcn_s_setprio(1);
      #pragma unroll
      for (int ms = 0; ms < 4; ms++)
        #pragma unroll
        for (int fs = 0; fs < 2; fs++)
          acc[ms][fs] = MFMA(af[ms], bfr[fs], acc[ms][fs]);
      __builtin_amdgcn_s_setprio(0);
    }
  }
  #undef STAGEG

  float bv2[2];
  #pragma unroll
  for (int fs = 0; fs < 2; fs++) bv2[fs] = bias[f0 + wf * 32 + fs * 16 + lo];
  #pragma unroll
  for (int ms = 0; ms < 4; ms++)
    #pragma unroll
    for (int fs = 0; fs < 2; fs++) {
      int f = f0 + wf * 32 + fs * 16 + lo;
      #pragma unroll
      for (int r = 0; r < 4; r++) {
        int m = mt * 128 + wm * 64 + ms * 16 + hi * 4 + r;
        Cout[(size_t)m * 1024 + f] = acc[ms][fs][r] + bv2[fs];
      }
    }
}

// ---------------- launch ----------------
extern "C" void kernel_launch(void* const* d_in, const int* in_sizes, int n_in,
                              void* d_out, int out_size, void* d_ws, size_t ws_size,
                              hipStream_t stream) {
  const float* x  = (const float*)d_in[0];
  const float* Wq = (const float*)d_in[1];
  const float* bq = (const float*)d_in[2];
  const float* Wk = (const float*)d_in[3];
  const float* bk = (const float*)d_in[4];
  const float* Wv = (const float*)d_in[5];
  const float* bv = (const float*)d_in[6];
  const float* Wo = (const float*)d_in[7];
  const float* bo = (const float*)d_in[8];
  float* out = (float*)d_out;
  char* ws = (char*)d_ws;

  bf16* xb  = (bf16*)(ws);
  bf16* wqb = (bf16*)(ws + 8388608);
  bf16* wkb = (bf16*)(ws + 10485760);
  bf16* wvb = (bf16*)(ws + 12582912);
  bf16* wob = (bf16*)(ws + 14680064);
  bf16* Qw  = (bf16*)(ws + 16777216);
  bf16* Kw  = (bf16*)(ws + 25165824);
  bf16* Vtw = (bf16*)(ws + 33554432);
  bf16* Ow  = (bf16*)(ws + 41943040);   // total 50331648 B

  k_cvt<<<dim3(2048, 5), 256, 0, stream>>>(x, Wq, Wk, Wv, Wo, xb, wqb, wkb, wvb, wob);
  k_gemm_qkv<<<dim3(32, 24), 256, 0, stream>>>(xb, wqb, wkb, wvb, bq, bk, bv, Qw, Kw, Vtw);
  k_attn<<<dim3(16, 32), 256, 0, stream>>>(Qw, Kw, Vtw, Ow);
  k_gemm_out<<<dim3(32, 8), 512, 0, stream>>>(Ow, wob, bo, out);
}

// Round 7
// 112.288 us; speedup vs baseline: 1.0581x; 1.0581x over previous
//
#include <hip/hip_runtime.h>
#include <hip/hip_bf16.h>
#include <stdint.h>

typedef __bf16 bf16;
typedef __bf16 bf16x8 __attribute__((ext_vector_type(8)));
typedef __bf16 bf16x4 __attribute__((ext_vector_type(4)));
typedef __bf16 bf16x2 __attribute__((ext_vector_type(2)));
typedef float  f32x4  __attribute__((ext_vector_type(4)));
typedef float  f32x16 __attribute__((ext_vector_type(16)));
typedef unsigned int uint;

#define MFMA(a,b,c)   __builtin_amdgcn_mfma_f32_16x16x32_bf16((a),(b),(c),0,0,0)
#define MFMA32(a,b,c) __builtin_amdgcn_mfma_f32_32x32x16_bf16((a),(b),(c),0,0,0)
#define EXP2(x)       __builtin_amdgcn_exp2f(x)

__device__ __forceinline__ void gload_lds16(const void* g, void* lds) {
  __builtin_amdgcn_global_load_lds(
      (const __attribute__((address_space(1))) uint32_t*)g,
      (__attribute__((address_space(3))) uint32_t*)lds, 16, 0, 0);
}

__device__ __forceinline__ uint pk_bf16(float lo, float hi) {
  bf16x2 v; v[0] = (bf16)lo; v[1] = (bf16)hi;
  return __builtin_bit_cast(uint, v);
}

// ---------------- convert fp32 -> bf16 (x + 4 weights) ----------------
__global__ __launch_bounds__(256) void k_cvt(
    const float* __restrict__ x,
    const float* __restrict__ wq, const float* __restrict__ wk,
    const float* __restrict__ wv, const float* __restrict__ wo,
    bf16* __restrict__ xb, bf16* __restrict__ wqb, bf16* __restrict__ wkb,
    bf16* __restrict__ wvb, bf16* __restrict__ wob)
{
  int r = blockIdx.y;
  const float* s; bf16* d; int n;
  switch (r) {
    case 0: s = x;  d = xb;  n = 4194304; break;
    case 1: s = wq; d = wqb; n = 1048576; break;
    case 2: s = wk; d = wkb; n = 1048576; break;
    case 3: s = wv; d = wvb; n = 1048576; break;
    default: s = wo; d = wob; n = 1048576; break;
  }
  int i = (blockIdx.x * 256 + threadIdx.x) * 8;
  if (i >= n) return;
  const float4* sp = (const float4*)(s + i);
  float4 a = sp[0], b = sp[1];
  bf16x8 o;
  o[0]=(bf16)a.x; o[1]=(bf16)a.y; o[2]=(bf16)a.z; o[3]=(bf16)a.w;
  o[4]=(bf16)b.x; o[5]=(bf16)b.y; o[6]=(bf16)b.z; o[7]=(bf16)b.w;
  *(bf16x8*)(d + i) = o;
}

// ---------------- fused QKV projection GEMM (2-phase, BK=32 dbuf, swizzled) -
// 128x128 tile, 4 waves, 32KB LDS -> 3 blocks/CU resident, 1 barrier/K-step.
// Q written scaled by log2(e)/32 into [b,h,n,d]; K into [b,h,n,d]; V into [b,h,d,n].
__global__ __launch_bounds__(256, 2) void k_gemm_qkv(
    const bf16* __restrict__ A,
    const bf16* __restrict__ Wq, const bf16* __restrict__ Wk, const bf16* __restrict__ Wv,
    const float* __restrict__ bq, const float* __restrict__ bk, const float* __restrict__ bv,
    bf16* __restrict__ Qw, bf16* __restrict__ Kw, bf16* __restrict__ Vtw)
{
  __shared__ __align__(16) char As[2][8192];
  __shared__ __align__(16) char Bs[2][8192];
  int tid = threadIdx.x;
  int wv4 = tid >> 6, l = tid & 63, lo = l & 15, hi = l >> 4;
  int mt = blockIdx.x;           // 0..31
  int ft = blockIdx.y;           // 0..23
  int wsel = ft >> 3;
  const bf16* W = (wsel == 0) ? Wq : (wsel == 1) ? Wk : Wv;
  const float* bias = (wsel == 0) ? bq : (wsel == 1) ? bk : bv;
  int f0 = (ft & 7) * 128;
  const bf16* Ab = A + (size_t)mt * 128 * 1024;
  const bf16* Wb = W + (size_t)f0 * 1024;
  int wm = wv4 >> 1, wf = wv4 & 1;
  f32x4 acc[4][4];
  #pragma unroll
  for (int i = 0; i < 4; i++)
    #pragma unroll
    for (int j = 0; j < 4; j++) acc[i][j] = (f32x4){0.f, 0.f, 0.f, 0.f};

  // staging BK=32: 512 slots/matrix; slot sp=(row<<2|s) <- global col 8*(s^(row&3))
  #define STAGEG(t, bi) {                                              \
    int k0 = (t) * 32;                                                 \
    _Pragma("unroll")                                                  \
    for (int p = 0; p < 2; p++) {                                      \
      int sp = p * 256 + tid;                                          \
      int row = sp >> 2, s = sp & 3;                                   \
      int gc = k0 + 8 * (s ^ (row & 3));                               \
      gload_lds16(Ab + (size_t)row * 1024 + gc, As[bi] + sp * 16);     \
      gload_lds16(Wb + (size_t)row * 1024 + gc, Bs[bi] + sp * 16);     \
    } }

  STAGEG(0, 0);
  for (int t = 0; t < 32; ++t) {
    __syncthreads();                          // buf t&1 ready, buf (t+1)&1 free
    if (t < 31) STAGEG(t + 1, (t + 1) & 1);   // loads fly under compute
    const char* Ac = As[t & 1];
    const char* Bc = Bs[t & 1];
    bf16x8 af[4], bfr[4];
    #pragma unroll
    for (int ms = 0; ms < 4; ms++) {
      int row = wm * 64 + ms * 16 + lo;
      af[ms] = *(const bf16x8*)(Ac + row * 64 + 16 * (hi ^ (row & 3)));
    }
    #pragma unroll
    for (int fs = 0; fs < 4; fs++) {
      int row = wf * 64 + fs * 16 + lo;
      bfr[fs] = *(const bf16x8*)(Bc + row * 64 + 16 * (hi ^ (row & 3)));
    }
    __builtin_amdgcn_s_setprio(1);
    #pragma unroll
    for (int ms = 0; ms < 4; ms++)
      #pragma unroll
      for (int fs = 0; fs < 4; fs++)
        acc[ms][fs] = MFMA(af[ms], bfr[fs], acc[ms][fs]);
    __builtin_amdgcn_s_setprio(0);
  }
  #undef STAGEG

  float bv4[4];
  #pragma unroll
  for (int fs = 0; fs < 4; fs++) bv4[fs] = bias[f0 + wf * 64 + fs * 16 + lo];
  #pragma unroll
  for (int ms = 0; ms < 4; ms++) {
    #pragma unroll
    for (int fs = 0; fs < 4; fs++) {
      int fl = f0 + wf * 64 + fs * 16 + lo;
      int h = fl >> 6, dd = fl & 63;
      #pragma unroll
      for (int r = 0; r < 4; r++) {
        int m = mt * 128 + wm * 64 + ms * 16 + hi * 4 + r;
        int b = m >> 11, n = m & 2047;
        float val = acc[ms][fs][r] + bv4[fs];
        if (wsel == 0)      Qw[(((size_t)(b * 16 + h) * 2048 + n) * 64) + dd] = (bf16)(val * 0.0450842199527801f);
        else if (wsel == 1) Kw[(((size_t)(b * 16 + h) * 2048 + n) * 64) + dd] = (bf16)val;
        else                Vtw[(((size_t)(b * 16 + h) * 64 + dd) * 2048) + n] = (bf16)val;
      }
    }
  }
}

// ---------------- flash attention v4: 32q/wave, 2 blocks/CU, dbuf, max-free --
__global__ __launch_bounds__(256, 2) void k_attn(
    const bf16* __restrict__ Q, const bf16* __restrict__ K,
    const bf16* __restrict__ Vt, bf16* __restrict__ O)
{
  __shared__ __align__(16) char Ks[2][8192];
  __shared__ __align__(16) char Vs[2][8192];
  int tid = threadIdx.x;
  int wid = tid >> 6, l = tid & 63;
  int lq = l & 31, hi1 = l >> 5;
  int qt = blockIdx.x, bh = blockIdx.y;
  int qg = qt * 128 + wid * 32 + lq;
  const bf16* Kb = K + (size_t)bh * 2048 * 64;
  const bf16* Vb = Vt + (size_t)bh * 64 * 2048;

  bf16x8 qf[4];
  const bf16* Qb = Q + ((size_t)bh * 2048 + qg) * 64 + hi1 * 8;
  #pragma unroll
  for (int c = 0; c < 4; c++) qf[c] = *(const bf16x8*)(Qb + 16 * c);

  f32x16 o0, o1, zz;
  #pragma unroll
  for (int r = 0; r < 16; r++) { zz[r] = 0.f; o0[r] = 0.f; o1[r] = 0.f; }
  float ls = 0.f;

  int srow = tid >> 3, slot = tid & 7;
  int swz = 16 * (slot ^ (srow & 7));
  int swk = lq & 7;
  uint4 k0r, k1r, v0r, v1r;
  #define STAGE(t) {                                                          \
    k0r = *(const uint4*)(Kb + (size_t)((t)*64 + srow) * 64 + slot * 8);      \
    k1r = *(const uint4*)(Kb + (size_t)((t)*64 + srow + 32) * 64 + slot * 8); \
    v0r = *(const uint4*)(Vb + (size_t)srow * 2048 + (t)*64 + slot * 8);      \
    v1r = *(const uint4*)(Vb + (size_t)(srow + 32) * 2048 + (t)*64 + slot * 8); }
  #define WRBUF(bi) {                                  \
    *(uint4*)(Ks[bi] + srow * 128 + swz)        = k0r; \
    *(uint4*)(Ks[bi] + (srow + 32) * 128 + swz) = k1r; \
    *(uint4*)(Vs[bi] + srow * 128 + swz)        = v0r; \
    *(uint4*)(Vs[bi] + (srow + 32) * 128 + swz) = v1r; }
  #define EXPSUM(S, T0, T1, T2, T3)                     \
    _Pragma("unroll")                                   \
    for (int r = 0; r < 16; r += 4) {                   \
      S[r]   = EXP2(S[r]);   T0 += S[r];                \
      S[r+1] = EXP2(S[r+1]); T1 += S[r+1];              \
      S[r+2] = EXP2(S[r+2]); T2 += S[r+2];              \
      S[r+3] = EXP2(S[r+3]); T3 += S[r+3];              \
    }
  #define PACK(dst, plo, phi)                                                \
    _Pragma("unroll")                                                        \
    for (int m = 0; m < 2; m++) {                                            \
      uint a0 = pk_bf16(plo[8*m+0], plo[8*m+1]);                             \
      uint b0 = pk_bf16(plo[8*m+4], plo[8*m+5]);                             \
      asm volatile("v_permlane32_swap_b32 %0, %1" : "+v"(a0), "+v"(b0));     \
      uint a1 = pk_bf16(plo[8*m+2], plo[8*m+3]);                             \
      uint b1 = pk_bf16(plo[8*m+6], plo[8*m+7]);                             \
      asm volatile("v_permlane32_swap_b32 %0, %1" : "+v"(a1), "+v"(b1));     \
      dst[m] = (uint4){a0, a1, b0, b1};                                      \
      uint c0 = pk_bf16(phi[8*m+0], phi[8*m+1]);                             \
      uint d0 = pk_bf16(phi[8*m+4], phi[8*m+5]);                             \
      asm volatile("v_permlane32_swap_b32 %0, %1" : "+v"(c0), "+v"(d0));     \
      uint c1 = pk_bf16(phi[8*m+2], phi[8*m+3]);                             \
      uint d1 = pk_bf16(phi[8*m+6], phi[8*m+7]);                             \
      asm volatile("v_permlane32_swap_b32 %0, %1" : "+v"(c1), "+v"(d1));     \
      dst[2+m] = (uint4){c0, c1, d0, d1};                                    \
    }

  STAGE(0);
  WRBUF(0);
  STAGE(1);

  for (int t = 0; t < 32; ++t) {
    __syncthreads();
    const char* Kc = Ks[t & 1];
    const char* Vc = Vs[t & 1];

    bf16x8 kf0[4], kf1[4];
    #pragma unroll
    for (int c = 0; c < 4; c++) {
      kf0[c] = *(const bf16x8*)(Kc + lq * 128 + 16 * ((2*c + hi1) ^ swk));
      kf1[c] = *(const bf16x8*)(Kc + (32 + lq) * 128 + 16 * ((2*c + hi1) ^ swk));
    }

    __builtin_amdgcn_s_setprio(1);
    f32x16 s0 = MFMA32(kf0[0], qf[0], zz);
    f32x16 s1 = MFMA32(kf1[0], qf[0], zz);
    #pragma unroll
    for (int c = 1; c < 4; c++) {
      s0 = MFMA32(kf0[c], qf[c], s0);
      s1 = MFMA32(kf1[c], qf[c], s1);
    }
    __builtin_amdgcn_s_setprio(0);

    float t0 = 0.f, t1 = 0.f, t2 = 0.f, t3 = 0.f;
    EXPSUM(s0, t0, t1, t2, t3);
    EXPSUM(s1, t0, t1, t2, t3);
    ls += (t0 + t1) + (t2 + t3);

    uint4 pf[4];
    PACK(pf, s0, s1);

    __builtin_amdgcn_s_setprio(1);
    #pragma unroll
    for (int c = 0; c < 4; c++) {
      bf16x8 pb = __builtin_bit_cast(bf16x8, pf[c]);
      bf16x8 vf0 = *(const bf16x8*)(Vc + lq * 128 + 16 * ((2*c + hi1) ^ swk));
      o0 = MFMA32(vf0, pb, o0);
      bf16x8 vf1 = *(const bf16x8*)(Vc + (32 + lq) * 128 + 16 * ((2*c + hi1) ^ swk));
      o1 = MFMA32(vf1, pb, o1);
    }
    __builtin_amdgcn_s_setprio(0);

    if (t < 31) {
      WRBUF((t + 1) & 1);
      if (t < 30) STAGE(t + 2);
    }
  }
  #undef STAGE
  #undef WRBUF

  float lsum = ls + __shfl_xor(ls, 32);
  float inv = 1.0f / lsum;
  int b = bh >> 4, h = bh & 15;
  bf16* Ob = O + ((size_t)(b * 2048 + qg)) * 1024 + h * 64 + hi1 * 4;
  #pragma unroll
  for (int g = 0; g < 4; g++) {
    bf16x4 w0, w1;
    #pragma unroll
    for (int j = 0; j < 4; j++) {
      w0[j] = (bf16)(o0[4*g+j] * inv);
      w1[j] = (bf16)(o1[4*g+j] * inv);
    }
    *(bf16x4*)(Ob + g * 8)      = w0;
    *(bf16x4*)(Ob + 32 + g * 8) = w1;
  }
}

// ---------------- output projection GEMM (2-phase pipelined, 512 thr) -------
// 128x128 tile, 8 waves (2Mx4F), BK=64; grid (32,8)=256 blocks -> 2 waves/SIMD.
__global__ __launch_bounds__(512, 1) void k_gemm_out(
    const bf16* __restrict__ A,      // O [4096][1024] bf16
    const bf16* __restrict__ W,      // Wo bf16 [1024][1024]
    const float* __restrict__ bias,  // bo
    float* __restrict__ Cout)        // [4096][1024] fp32
{
  __shared__ __align__(16) char As[2][16384];
  __shared__ __align__(16) char Bs[2][16384];
  int tid = threadIdx.x;
  int wid = tid >> 6, l = tid & 63, lo = l & 15, hi = l >> 4;
  int mt = blockIdx.x;           // 0..31
  int f0 = blockIdx.y * 128;     // 0..7 tiles
  const bf16* Ab = A + (size_t)mt * 128 * 1024;
  const bf16* Wb = W + (size_t)f0 * 1024;
  int wm = wid >> 2, wf = wid & 3;   // 2M x 4F; per-wave out 64x32
  f32x4 acc[4][2];
  #pragma unroll
  for (int i = 0; i < 4; i++)
    #pragma unroll
    for (int j = 0; j < 2; j++) acc[i][j] = (f32x4){0.f, 0.f, 0.f, 0.f};

  #define STAGEG(t, bi) {                                              \
    int k0 = (t) * 64;                                                 \
    _Pragma("unroll")                                                  \
    for (int p = 0; p < 2; p++) {                                      \
      int sp = p * 512 + tid;                                          \
      int row = sp >> 3, s = sp & 7;                                   \
      int gc = k0 + 8 * (s ^ (row & 7));                               \
      gload_lds16(Ab + (size_t)row * 1024 + gc, As[bi] + sp * 16);     \
      gload_lds16(Wb + (size_t)row * 1024 + gc, Bs[bi] + sp * 16);     \
    } }

  STAGEG(0, 0);
  for (int t = 0; t < 16; ++t) {
    __syncthreads();
    if (t < 15) STAGEG(t + 1, (t + 1) & 1);
    const char* Ac = As[t & 1];
    const char* Bc = Bs[t & 1];
    #pragma unroll
    for (int kk = 0; kk < 2; kk++) {
      bf16x8 af[4], bfr[2];
      #pragma unroll
      for (int ms = 0; ms < 4; ms++) {
        int row = wm * 64 + ms * 16 + lo;
        af[ms] = *(const bf16x8*)(Ac + row * 128 + 16 * ((kk * 4 + hi) ^ (row & 7)));
      }
      #pragma unroll
      for (int fs = 0; fs < 2; fs++) {
        int row = wf * 32 + fs * 16 + lo;
        bfr[fs] = *(const bf16x8*)(Bc + row * 128 + 16 * ((kk * 4 + hi) ^ (row & 7)));
      }
      __builtin_amdgcn_s_setprio(1);
      #pragma unroll
      for (int ms = 0; ms < 4; ms++)
        #pragma unroll
        for (int fs = 0; fs < 2; fs++)
          acc[ms][fs] = MFMA(af[ms], bfr[fs], acc[ms][fs]);
      __builtin_amdgcn_s_setprio(0);
    }
  }
  #undef STAGEG

  float bv2[2];
  #pragma unroll
  for (int fs = 0; fs < 2; fs++) bv2[fs] = bias[f0 + wf * 32 + fs * 16 + lo];
  #pragma unroll
  for (int ms = 0; ms < 4; ms++)
    #pragma unroll
    for (int fs = 0; fs < 2; fs++) {
      int f = f0 + wf * 32 + fs * 16 + lo;
      #pragma unroll
      for (int r = 0; r < 4; r++) {
        int m = mt * 128 + wm * 64 + ms * 16 + hi * 4 + r;
        Cout[(size_t)m * 1024 + f] = acc[ms][fs][r] + bv2[fs];
      }
    }
}

// ---------------- launch ----------------
extern "C" void kernel_launch(void* const* d_in, const int* in_sizes, int n_in,
                              void* d_out, int out_size, void* d_ws, size_t ws_size,
                              hipStream_t stream) {
  const float* x  = (const float*)d_in[0];
  const float* Wq = (const float*)d_in[1];
  const float* bq = (const float*)d_in[2];
  const float* Wk = (const float*)d_in[3];
  const float* bk = (const float*)d_in[4];
  const float* Wv = (const float*)d_in[5];
  const float* bv = (const float*)d_in[6];
  const float* Wo = (const float*)d_in[7];
  const float* bo = (const float*)d_in[8];
  float* out = (float*)d_out;
  char* ws = (char*)d_ws;

  bf16* xb  = (bf16*)(ws);
  bf16* wqb = (bf16*)(ws + 8388608);
  bf16* wkb = (bf16*)(ws + 10485760);
  bf16* wvb = (bf16*)(ws + 12582912);
  bf16* wob = (bf16*)(ws + 14680064);
  bf16* Qw  = (bf16*)(ws + 16777216);
  bf16* Kw  = (bf16*)(ws + 25165824);
  bf16* Vtw = (bf16*)(ws + 33554432);
  bf16* Ow  = (bf16*)(ws + 41943040);   // total 50331648 B

  k_cvt<<<dim3(2048, 5), 256, 0, stream>>>(x, Wq, Wk, Wv, Wo, xb, wqb, wkb, wvb, wob);
  k_gemm_qkv<<<dim3(32, 24), 256, 0, stream>>>(xb, wqb, wkb, wvb, bq, bk, bv, Qw, Kw, Vtw);
  k_attn<<<dim3(16, 32), 256, 0, stream>>>(Qw, Kw, Vtw, Ow);
  k_gemm_out<<<dim3(32, 8), 512, 0, stream>>>(Ow, wob, bo, out);
}

// Round 8
// 106.135 us; speedup vs baseline: 1.1194x; 1.0580x over previous
//
#include <hip/hip_runtime.h>
#include <hip/hip_bf16.h>
#include <stdint.h>

typedef __bf16 bf16;
typedef __bf16 bf16x8 __attribute__((ext_vector_type(8)));
typedef __bf16 bf16x4 __attribute__((ext_vector_type(4)));
typedef __bf16 bf16x2 __attribute__((ext_vector_type(2)));
typedef float  f32x4  __attribute__((ext_vector_type(4)));
typedef float  f32x16 __attribute__((ext_vector_type(16)));
typedef unsigned int uint;

#define MFMA(a,b,c)   __builtin_amdgcn_mfma_f32_16x16x32_bf16((a),(b),(c),0,0,0)
#define MFMA32(a,b,c) __builtin_amdgcn_mfma_f32_32x32x16_bf16((a),(b),(c),0,0,0)
#define EXP2(x)       __builtin_amdgcn_exp2f(x)

__device__ __forceinline__ void gload_lds16(const void* g, void* lds) {
  __builtin_amdgcn_global_load_lds(
      (const __attribute__((address_space(1))) uint32_t*)g,
      (__attribute__((address_space(3))) uint32_t*)lds, 16, 0, 0);
}

__device__ __forceinline__ uint pk_bf16(float lo, float hi) {
  bf16x2 v; v[0] = (bf16)lo; v[1] = (bf16)hi;
  return __builtin_bit_cast(uint, v);
}

// ---------------- convert fp32 -> bf16 (x + 4 weights) ----------------
__global__ __launch_bounds__(256) void k_cvt(
    const float* __restrict__ x,
    const float* __restrict__ wq, const float* __restrict__ wk,
    const float* __restrict__ wv, const float* __restrict__ wo,
    bf16* __restrict__ xb, bf16* __restrict__ wqb, bf16* __restrict__ wkb,
    bf16* __restrict__ wvb, bf16* __restrict__ wob)
{
  int r = blockIdx.y;
  const float* s; bf16* d; int n;
  switch (r) {
    case 0: s = x;  d = xb;  n = 4194304; break;
    case 1: s = wq; d = wqb; n = 1048576; break;
    case 2: s = wk; d = wkb; n = 1048576; break;
    case 3: s = wv; d = wvb; n = 1048576; break;
    default: s = wo; d = wob; n = 1048576; break;
  }
  int i = (blockIdx.x * 256 + threadIdx.x) * 8;
  if (i >= n) return;
  const float4* sp = (const float4*)(s + i);
  float4 a = sp[0], b = sp[1];
  bf16x8 o;
  o[0]=(bf16)a.x; o[1]=(bf16)a.y; o[2]=(bf16)a.z; o[3]=(bf16)a.w;
  o[4]=(bf16)b.x; o[5]=(bf16)b.y; o[6]=(bf16)b.z; o[7]=(bf16)b.w;
  *(bf16x8*)(d + i) = o;
}

// ---------------- fused QKV projection GEMM (2-phase, BK=32 dbuf) -----------
// First MFMA operand = W for Q/K (so f lands in reg-dim -> coalesced 8B stores),
// = x for V (so n lands in reg-dim for the V^T layout). XCD-swizzled blocks.
__global__ __launch_bounds__(256, 2) void k_gemm_qkv(
    const bf16* __restrict__ A,
    const bf16* __restrict__ Wq, const bf16* __restrict__ Wk, const bf16* __restrict__ Wv,
    const float* __restrict__ bq, const float* __restrict__ bk, const float* __restrict__ bv,
    bf16* __restrict__ Qw, bf16* __restrict__ Kw, bf16* __restrict__ Vtw)
{
  __shared__ __align__(16) char As[2][8192];
  __shared__ __align__(16) char Bs[2][8192];
  int tid = threadIdx.x;
  int wv4 = tid >> 6, l = tid & 63, lo = l & 15, hi = l >> 4;
  // XCD swizzle: flat f (x-major), xcd = f&7 gets mt stripe 4*xcd..+3, all ft
  int f = blockIdx.y * 32 + blockIdx.x;        // 0..767
  int xcd = f & 7, i8 = f >> 3;                // i8: 0..95
  int mt = xcd * 4 + (i8 & 3);                 // 0..31
  int ft = i8 >> 2;                            // 0..23
  int wsel = ft >> 3;
  const bf16* W = (wsel == 0) ? Wq : (wsel == 1) ? Wk : Wv;
  const float* bias = (wsel == 0) ? bq : (wsel == 1) ? bk : bv;
  int f0 = (ft & 7) * 128;
  const bf16* Ab = A + (size_t)mt * 128 * 1024;
  const bf16* Wb = W + (size_t)f0 * 1024;
  const bf16* Pa = (wsel < 2) ? Wb : Ab;   // staged into As (first operand)
  const bf16* Pb = (wsel < 2) ? Ab : Wb;   // staged into Bs (second operand)
  int wm = wv4 >> 1, wf = wv4 & 1;
  f32x4 acc[4][4];
  #pragma unroll
  for (int i = 0; i < 4; i++)
    #pragma unroll
    for (int j = 0; j < 4; j++) acc[i][j] = (f32x4){0.f, 0.f, 0.f, 0.f};

  // staging BK=32: 512 slots/matrix; slot sp=(row<<2|s) <- gcol 8*(s^((row>>1)&3))
  #define STAGEG(t, bi) {                                              \
    int k0 = (t) * 32;                                                 \
    _Pragma("unroll")                                                  \
    for (int p = 0; p < 2; p++) {                                      \
      int sp = p * 256 + tid;                                          \
      int row = sp >> 2, s = sp & 3;                                   \
      int gc = k0 + 8 * (s ^ ((row >> 1) & 3));                        \
      gload_lds16(Pa + (size_t)row * 1024 + gc, As[bi] + sp * 16);     \
      gload_lds16(Pb + (size_t)row * 1024 + gc, Bs[bi] + sp * 16);     \
    } }

  STAGEG(0, 0);
  for (int t = 0; t < 32; ++t) {
    __syncthreads();                          // buf t&1 ready, buf (t+1)&1 free
    if (t < 31) STAGEG(t + 1, (t + 1) & 1);   // loads fly under compute
    const char* Ac = As[t & 1];
    const char* Bc = Bs[t & 1];
    bf16x8 af[4], bfr[4];
    #pragma unroll
    for (int ms = 0; ms < 4; ms++) {
      int row = wm * 64 + ms * 16 + lo;
      af[ms] = *(const bf16x8*)(Ac + row * 64 + 16 * (hi ^ ((row >> 1) & 3)));
    }
    #pragma unroll
    for (int fs = 0; fs < 4; fs++) {
      int row = wf * 64 + fs * 16 + lo;
      bfr[fs] = *(const bf16x8*)(Bc + row * 64 + 16 * (hi ^ ((row >> 1) & 3)));
    }
    __builtin_amdgcn_s_setprio(1);
    #pragma unroll
    for (int ms = 0; ms < 4; ms++)
      #pragma unroll
      for (int fs = 0; fs < 4; fs++)
        acc[ms][fs] = MFMA(af[ms], bfr[fs], acc[ms][fs]);
    __builtin_amdgcn_s_setprio(0);
  }
  #undef STAGEG

  if (wsel < 2) {
    // D[f: wm*64+ms*16+hi*4+r][n: wf*64+fs*16+lo] -> [b,h,n,d], 8B stores
    bf16* Outp = (wsel == 0) ? Qw : Kw;
    float qs = (wsel == 0) ? 0.0450842199527801f : 1.0f;
    #pragma unroll
    for (int ms = 0; ms < 4; ms++) {
      int fl = f0 + wm * 64 + ms * 16 + hi * 4;
      int h = fl >> 6, dd = fl & 63;
      float4 b4 = *(const float4*)(bias + fl);
      #pragma unroll
      for (int fs = 0; fs < 4; fs++) {
        int m = mt * 128 + wf * 64 + fs * 16 + lo;
        int b = m >> 11, nn = m & 2047;
        bf16x4 w;
        #pragma unroll
        for (int r = 0; r < 4; r++)
          w[r] = (bf16)((acc[ms][fs][r] + ((const float*)&b4)[r]) * qs);
        *(bf16x4*)(Outp + (((size_t)(b * 16 + h) * 2048 + nn) * 64) + dd) = w;
      }
    }
  } else {
    // D[n: wm*64+ms*16+hi*4+r][f: wf*64+fs*16+lo] -> V^T [b,h,d,n], 8B stores
    #pragma unroll
    for (int fs = 0; fs < 4; fs++) {
      int fl = f0 + wf * 64 + fs * 16 + lo;
      int h = fl >> 6, dd = fl & 63;
      float bb = bias[fl];
      #pragma unroll
      for (int ms = 0; ms < 4; ms++) {
        int m = mt * 128 + wm * 64 + ms * 16 + hi * 4;
        int b = m >> 11, nn = m & 2047;
        bf16x4 w;
        #pragma unroll
        for (int r = 0; r < 4; r++) w[r] = (bf16)(acc[ms][fs][r] + bb);
        *(bf16x4*)(Vtw + (((size_t)(b * 16 + h) * 64 + dd) * 2048) + nn) = w;
      }
    }
  }
}

// ---------------- flash attention v4: 32q/wave, 2 blocks/CU, dbuf, max-free --
// XCD swizzle: each XCD owns 4 heads (2MB K/V in its L2, reused by 16 qt blocks).
__global__ __launch_bounds__(256, 2) void k_attn(
    const bf16* __restrict__ Q, const bf16* __restrict__ K,
    const bf16* __restrict__ Vt, bf16* __restrict__ O)
{
  __shared__ __align__(16) char Ks[2][8192];
  __shared__ __align__(16) char Vs[2][8192];
  int tid = threadIdx.x;
  int wid = tid >> 6, l = tid & 63;
  int lq = l & 31, hi1 = l >> 5;
  int f = blockIdx.y * 16 + blockIdx.x;        // 0..511
  int xcd = f & 7, i8 = f >> 3;                // i8: 0..63
  int bh = xcd * 4 + (i8 & 3);                 // 0..31
  int qt = i8 >> 2;                            // 0..15
  int qg = qt * 128 + wid * 32 + lq;
  const bf16* Kb = K + (size_t)bh * 2048 * 64;
  const bf16* Vb = Vt + (size_t)bh * 64 * 2048;

  bf16x8 qf[4];
  const bf16* Qb = Q + ((size_t)bh * 2048 + qg) * 64 + hi1 * 8;
  #pragma unroll
  for (int c = 0; c < 4; c++) qf[c] = *(const bf16x8*)(Qb + 16 * c);

  f32x16 o0, o1, zz;
  #pragma unroll
  for (int r = 0; r < 16; r++) { zz[r] = 0.f; o0[r] = 0.f; o1[r] = 0.f; }
  float ls = 0.f;

  int srow = tid >> 3, slot = tid & 7;
  int swz = 16 * (slot ^ (srow & 7));
  int swk = lq & 7;
  uint4 k0r, k1r, v0r, v1r;
  #define STAGE(t) {                                                          \
    k0r = *(const uint4*)(Kb + (size_t)((t)*64 + srow) * 64 + slot * 8);      \
    k1r = *(const uint4*)(Kb + (size_t)((t)*64 + srow + 32) * 64 + slot * 8); \
    v0r = *(const uint4*)(Vb + (size_t)srow * 2048 + (t)*64 + slot * 8);      \
    v1r = *(const uint4*)(Vb + (size_t)(srow + 32) * 2048 + (t)*64 + slot * 8); }
  #define WRBUF(bi) {                                  \
    *(uint4*)(Ks[bi] + srow * 128 + swz)        = k0r; \
    *(uint4*)(Ks[bi] + (srow + 32) * 128 + swz) = k1r; \
    *(uint4*)(Vs[bi] + srow * 128 + swz)        = v0r; \
    *(uint4*)(Vs[bi] + (srow + 32) * 128 + swz) = v1r; }
  #define EXPSUM(S, T0, T1, T2, T3)                     \
    _Pragma("unroll")                                   \
    for (int r = 0; r < 16; r += 4) {                   \
      S[r]   = EXP2(S[r]);   T0 += S[r];                \
      S[r+1] = EXP2(S[r+1]); T1 += S[r+1];              \
      S[r+2] = EXP2(S[r+2]); T2 += S[r+2];              \
      S[r+3] = EXP2(S[r+3]); T3 += S[r+3];              \
    }
  #define PACK(dst, plo, phi)                                                \
    _Pragma("unroll")                                                        \
    for (int m = 0; m < 2; m++) {                                            \
      uint a0 = pk_bf16(plo[8*m+0], plo[8*m+1]);                             \
      uint b0 = pk_bf16(plo[8*m+4], plo[8*m+5]);                             \
      asm volatile("v_permlane32_swap_b32 %0, %1" : "+v"(a0), "+v"(b0));     \
      uint a1 = pk_bf16(plo[8*m+2], plo[8*m+3]);                             \
      uint b1 = pk_bf16(plo[8*m+6], plo[8*m+7]);                             \
      asm volatile("v_permlane32_swap_b32 %0, %1" : "+v"(a1), "+v"(b1));     \
      dst[m] = (uint4){a0, a1, b0, b1};                                      \
      uint c0 = pk_bf16(phi[8*m+0], phi[8*m+1]);                             \
      uint d0 = pk_bf16(phi[8*m+4], phi[8*m+5]);                             \
      asm volatile("v_permlane32_swap_b32 %0, %1" : "+v"(c0), "+v"(d0));     \
      uint c1 = pk_bf16(phi[8*m+2], phi[8*m+3]);                             \
      uint d1 = pk_bf16(phi[8*m+6], phi[8*m+7]);                             \
      asm volatile("v_permlane32_swap_b32 %0, %1" : "+v"(c1), "+v"(d1));     \
      dst[2+m] = (uint4){c0, c1, d0, d1};                                    \
    }

  STAGE(0);
  WRBUF(0);
  STAGE(1);

  for (int t = 0; t < 32; ++t) {
    __syncthreads();
    const char* Kc = Ks[t & 1];
    const char* Vc = Vs[t & 1];

    bf16x8 kf0[4], kf1[4];
    #pragma unroll
    for (int c = 0; c < 4; c++) {
      kf0[c] = *(const bf16x8*)(Kc + lq * 128 + 16 * ((2*c + hi1) ^ swk));
      kf1[c] = *(const bf16x8*)(Kc + (32 + lq) * 128 + 16 * ((2*c + hi1) ^ swk));
    }

    __builtin_amdgcn_s_setprio(1);
    f32x16 s0 = MFMA32(kf0[0], qf[0], zz);
    f32x16 s1 = MFMA32(kf1[0], qf[0], zz);
    #pragma unroll
    for (int c = 1; c < 4; c++) {
      s0 = MFMA32(kf0[c], qf[c], s0);
      s1 = MFMA32(kf1[c], qf[c], s1);
    }
    __builtin_amdgcn_s_setprio(0);

    float t0 = 0.f, t1 = 0.f, t2 = 0.f, t3 = 0.f;
    EXPSUM(s0, t0, t1, t2, t3);
    EXPSUM(s1, t0, t1, t2, t3);
    ls += (t0 + t1) + (t2 + t3);

    uint4 pf[4];
    PACK(pf, s0, s1);

    __builtin_amdgcn_s_setprio(1);
    #pragma unroll
    for (int c = 0; c < 4; c++) {
      bf16x8 pb = __builtin_bit_cast(bf16x8, pf[c]);
      bf16x8 vf0 = *(const bf16x8*)(Vc + lq * 128 + 16 * ((2*c + hi1) ^ swk));
      o0 = MFMA32(vf0, pb, o0);
      bf16x8 vf1 = *(const bf16x8*)(Vc + (32 + lq) * 128 + 16 * ((2*c + hi1) ^ swk));
      o1 = MFMA32(vf1, pb, o1);
    }
    __builtin_amdgcn_s_setprio(0);

    if (t < 31) {
      WRBUF((t + 1) & 1);
      if (t < 30) STAGE(t + 2);
    }
  }
  #undef STAGE
  #undef WRBUF

  float lsum = ls + __shfl_xor(ls, 32);
  float inv = 1.0f / lsum;
  int b = bh >> 4, h = bh & 15;
  bf16* Ob = O + ((size_t)(b * 2048 + qg)) * 1024 + h * 64 + hi1 * 4;
  #pragma unroll
  for (int g = 0; g < 4; g++) {
    bf16x4 w0, w1;
    #pragma unroll
    for (int j = 0; j < 4; j++) {
      w0[j] = (bf16)(o0[4*g+j] * inv);
      w1[j] = (bf16)(o1[4*g+j] * inv);
    }
    *(bf16x4*)(Ob + g * 8)      = w0;
    *(bf16x4*)(Ob + 32 + g * 8) = w1;
  }
}

// ---------------- output projection GEMM (2-phase, 512 thr, W-first) --------
// First operand = W -> f in reg-dim -> float4 C-stores. XCD-swizzled.
__global__ __launch_bounds__(512, 1) void k_gemm_out(
    const bf16* __restrict__ A,      // O [4096][1024] bf16
    const bf16* __restrict__ W,      // Wo bf16 [1024][1024]
    const float* __restrict__ bias,  // bo
    float* __restrict__ Cout)        // [4096][1024] fp32
{
  __shared__ __align__(16) char As[2][16384];
  __shared__ __align__(16) char Bs[2][16384];
  int tid = threadIdx.x;
  int wid = tid >> 6, l = tid & 63, lo = l & 15, hi = l >> 4;
  int f = blockIdx.y * 32 + blockIdx.x;        // 0..255
  int xcd = f & 7, i8 = f >> 3;                // i8: 0..31
  int mt = xcd * 4 + (i8 & 3);                 // 0..31
  int f0 = (i8 >> 2) * 128;                    // 0..7 tiles
  const bf16* Ab = A + (size_t)mt * 128 * 1024;
  const bf16* Wb = W + (size_t)f0 * 1024;
  int wm2 = wid >> 2, wf4 = wid & 3;   // 2M x 4F; per-wave out 64m x 32f
  f32x4 acc[2][4];                     // [f-sub][m-sub]
  #pragma unroll
  for (int i = 0; i < 2; i++)
    #pragma unroll
    for (int j = 0; j < 4; j++) acc[i][j] = (f32x4){0.f, 0.f, 0.f, 0.f};

  #define STAGEG(t, bi) {                                              \
    int k0 = (t) * 64;                                                 \
    _Pragma("unroll")                                                  \
    for (int p = 0; p < 2; p++) {                                      \
      int sp = p * 512 + tid;                                          \
      int row = sp >> 3, s = sp & 7;                                   \
      int gc = k0 + 8 * (s ^ (row & 7));                               \
      gload_lds16(Wb + (size_t)row * 1024 + gc, As[bi] + sp * 16);     \
      gload_lds16(Ab + (size_t)row * 1024 + gc, Bs[bi] + sp * 16);     \
    } }

  STAGEG(0, 0);
  for (int t = 0; t < 16; ++t) {
    __syncthreads();
    if (t < 15) STAGEG(t + 1, (t + 1) & 1);
    const char* Ac = As[t & 1];   // W tile (first operand)
    const char* Bc = Bs[t & 1];   // A tile (second operand)
    #pragma unroll
    for (int kk = 0; kk < 2; kk++) {
      bf16x8 wfr[2], afr[4];
      #pragma unroll
      for (int i = 0; i < 2; i++) {
        int row = wf4 * 32 + i * 16 + lo;
        wfr[i] = *(const bf16x8*)(Ac + row * 128 + 16 * ((kk * 4 + hi) ^ (row & 7)));
      }
      #pragma unroll
      for (int j = 0; j < 4; j++) {
        int row = wm2 * 64 + j * 16 + lo;
        afr[j] = *(const bf16x8*)(Bc + row * 128 + 16 * ((kk * 4 + hi) ^ (row & 7)));
      }
      __builtin_amdgcn_s_setprio(1);
      #pragma unroll
      for (int i = 0; i < 2; i++)
        #pragma unroll
        for (int j = 0; j < 4; j++)
          acc[i][j] = MFMA(wfr[i], afr[j], acc[i][j]);
      __builtin_amdgcn_s_setprio(0);
    }
  }
  #undef STAGEG

  // D[f: wf4*32+i*16+hi*4+r][m: wm2*64+j*16+lo] -> float4 stores
  #pragma unroll
  for (int i = 0; i < 2; i++) {
    int fl = f0 + wf4 * 32 + i * 16 + hi * 4;
    float4 b4 = *(const float4*)(bias + fl);
    #pragma unroll
    for (int j = 0; j < 4; j++) {
      int m = mt * 128 + wm2 * 64 + j * 16 + lo;
      float4 o;
      o.x = acc[i][j][0] + b4.x;
      o.y = acc[i][j][1] + b4.y;
      o.z = acc[i][j][2] + b4.z;
      o.w = acc[i][j][3] + b4.w;
      *(float4*)(Cout + (size_t)m * 1024 + fl) = o;
    }
  }
}

// ---------------- launch ----------------
extern "C" void kernel_launch(void* const* d_in, const int* in_sizes, int n_in,
                              void* d_out, int out_size, void* d_ws, size_t ws_size,
                              hipStream_t stream) {
  const float* x  = (const float*)d_in[0];
  const float* Wq = (const float*)d_in[1];
  const float* bq = (const float*)d_in[2];
  const float* Wk = (const float*)d_in[3];
  const float* bk = (const float*)d_in[4];
  const float* Wv = (const float*)d_in[5];
  const float* bv = (const float*)d_in[6];
  const float* Wo = (const float*)d_in[7];
  const float* bo = (const float*)d_in[8];
  float* out = (float*)d_out;
  char* ws = (char*)d_ws;

  bf16* xb  = (bf16*)(ws);
  bf16* wqb = (bf16*)(ws + 8388608);
  bf16* wkb = (bf16*)(ws + 10485760);
  bf16* wvb = (bf16*)(ws + 12582912);
  bf16* wob = (bf16*)(ws + 14680064);
  bf16* Qw  = (bf16*)(ws + 16777216);
  bf16* Kw  = (bf16*)(ws + 25165824);
  bf16* Vtw = (bf16*)(ws + 33554432);
  bf16* Ow  = (bf16*)(ws + 41943040);   // total 50331648 B

  k_cvt<<<dim3(2048, 5), 256, 0, stream>>>(x, Wq, Wk, Wv, Wo, xb, wqb, wkb, wvb, wob);
  k_gemm_qkv<<<dim3(32, 24), 256, 0, stream>>>(xb, wqb, wkb, wvb, bq, bk, bv, Qw, Kw, Vtw);
  k_attn<<<dim3(16, 32), 256, 0, stream>>>(Qw, Kw, Vtw, Ow);
  k_gemm_out<<<dim3(32, 8), 512, 0, stream>>>(Ow, wob, bo, out);
}